// Round 9
// baseline (227.944 us; speedup 1.0000x reference)
//
#include <hip/hip_runtime.h>
#include <hip/hip_bf16.h>
#include <stdint.h>

#define NEG_INF -100000000.0f

typedef __attribute__((ext_vector_type(8))) short bf16x8;
typedef __attribute__((ext_vector_type(4))) float f32x4;
typedef __attribute__((ext_vector_type(4))) int i32x4;

// lgkm-only barrier: does NOT drain in-flight global (NT) stores, unlike
// __syncthreads. sched_barrier(0) pins code motion (rule #18).
#define LGKM_BAR()                                                \
    do {                                                          \
        asm volatile("s_waitcnt lgkmcnt(0)" ::: "memory");        \
        __builtin_amdgcn_s_barrier();                             \
        __builtin_amdgcn_sched_barrier(0);                        \
    } while (0)

// vmcnt drain + barrier (for global_load_lds staging completion)
#define VM_BAR()                                                  \
    do {                                                          \
        asm volatile("s_waitcnt vmcnt(0)" ::: "memory");          \
        __builtin_amdgcn_s_barrier();                             \
        __builtin_amdgcn_sched_barrier(0);                        \
    } while (0)

#define GLOAD_LDS16(gp, lp)                                                      \
    __builtin_amdgcn_global_load_lds(                                            \
        (const __attribute__((address_space(1))) void*)(gp),                     \
        (__attribute__((address_space(3))) void*)(lp), 16, 0, 0)

static __device__ __forceinline__ short f2bf(float x) {
    unsigned u = __float_as_uint(x);
    u = u + 0x7FFFu + ((u >> 16) & 1u);
    return (short)(u >> 16);
}

// ---------------- kernel 1: transpose + bf16-convert weights ----------------
__global__ void wtrans_kernel(const float* __restrict__ wq, const float* __restrict__ wk,
                              short* __restrict__ wtq, short* __restrict__ wtk) {
    __shared__ float tile[32][33];
    const float* w = blockIdx.z ? wk : wq;
    short* wt = blockIdx.z ? wtk : wtq;
    float scale = blockIdx.z ? 1.0f : 0.0625f;
    int tx = threadIdx.x, ty = threadIdx.y;
    int c0 = blockIdx.x * 32;
    int k0 = blockIdx.y * 32;
#pragma unroll
    for (int i = 0; i < 4; i++)
        tile[ty + i * 8][tx] = w[(k0 + ty + i * 8) * 256 + c0 + tx];
    __syncthreads();
#pragma unroll
    for (int i = 0; i < 4; i++)
        wt[(c0 + ty + i * 8) * 256 + k0 + tx] = f2bf(tile[tx][ty + i * 8] * scale);
}

// ---------------- kernel 2: projection GEMM + (y==2) mask bit-pack ----------------
// y=0: Q -> fragment layout [b][dc 8][row 1024][ks 32] bf16
// y=1: K -> strip-swizzled  [b][dc 8][strip s 4][row 1024][16B], s = g ^ (row&3)
//      (so a LINEAR global->LDS copy of a 64KB chunk gives bank-conflict-free
//       fragment reads in attn)
// y=2: pack mask; word (row,j) bit (i*4+c) = mask[row][j*4+i*128+c]
__global__ __launch_bounds__(512, 4)
void proj_kernel(const float* __restrict__ qin, const float* __restrict__ kin,
                 const short* __restrict__ wtq, const short* __restrict__ wtk,
                 short* __restrict__ Qb, short* __restrict__ Kb,
                 const int* __restrict__ mask, unsigned* __restrict__ pmask) {
    if (blockIdx.y == 2) {
        int t = threadIdx.x;
        size_t row = (size_t)blockIdx.x * 64 + (t >> 3);
        int seg8 = t & 7;
        const int* mrow = mask + row * 1024;
#pragma unroll
        for (int jj = 0; jj < 4; jj++) {
            int j = seg8 + jj * 8;
            unsigned v = 0;
#pragma unroll
            for (int i = 0; i < 8; i++) {
                i32x4 x = __builtin_nontemporal_load(
                    reinterpret_cast<const i32x4*>(mrow + j * 4 + i * 128));
                unsigned nib = (unsigned)(x.x | (x.y << 1) | (x.z << 2) | (x.w << 3));
                v |= nib << (i * 4);
            }
            pmask[row * 32 + j] = v;
        }
        return;
    }

    const float* x  = blockIdx.y ? kin : qin;
    const short* wt = blockIdx.y ? wtk : wtq;
    short* outp     = blockIdx.y ? Kb  : Qb;

    __shared__ __align__(16) short sbuf[64 * 296];
    short* xlds = sbuf;                // [64 row][32 k]
    short* wlds = sbuf + 2048;         // [256 c][32 k]

    int t = threadIdx.x;
    int lane = t & 63, w = t >> 6;
    int l15 = lane & 15, g = lane >> 4;
    int rowbase = blockIdx.x * 64;

    f32x4 zero = {0.f, 0.f, 0.f, 0.f};
    f32x4 acc[4][2];
#pragma unroll
    for (int m = 0; m < 4; m++)
#pragma unroll
        for (int n = 0; n < 2; n++) acc[m][n] = zero;

    for (int dc = 0; dc < 8; dc++) {
        __syncthreads();
        {
            int row = t >> 3, seg = t & 7;
            f32x4 v = __builtin_nontemporal_load(
                reinterpret_cast<const f32x4*>(x + (size_t)(rowbase + row) * 256 + dc * 32 + seg * 4));
            short4 bb;
            bb.x = f2bf(v.x); bb.y = f2bf(v.y); bb.z = f2bf(v.z); bb.w = f2bf(v.w);
            *reinterpret_cast<short4*>(&xlds[row * 32 + seg * 4]) = bb;
        }
#pragma unroll
        for (int i = 0; i < 2; i++) {
            int idx = i * 512 + t;
            int c = idx >> 2, seg = idx & 3;
            int4 v = *reinterpret_cast<const int4*>(wt + c * 256 + dc * 32 + seg * 8);
            *reinterpret_cast<int4*>(&wlds[idx * 8]) = v;
        }
        __syncthreads();

        bf16x8 a[4], bfr[2];
#pragma unroll
        for (int m = 0; m < 4; m++)
            a[m] = *reinterpret_cast<const bf16x8*>(&xlds[(m * 16 + l15) * 32 + g * 8]);
#pragma unroll
        for (int n = 0; n < 2; n++) {
            int c = w * 32 + n * 16 + l15;
            bfr[n] = *reinterpret_cast<const bf16x8*>(&wlds[c * 32 + g * 8]);
        }
#pragma unroll
        for (int m = 0; m < 4; m++)
#pragma unroll
            for (int n = 0; n < 2; n++)
                acc[m][n] = __builtin_amdgcn_mfma_f32_16x16x32_bf16(a[m], bfr[n], acc[m][n], 0, 0, 0);
    }

    __syncthreads();
#pragma unroll
    for (int m = 0; m < 4; m++)
#pragma unroll
        for (int n = 0; n < 2; n++) {
            int col = w * 32 + n * 16 + l15;
#pragma unroll
            for (int r = 0; r < 4; r++)
                sbuf[(m * 16 + g * 4 + r) * 296 + col] = f2bf(acc[m][n][r]);
        }
    __syncthreads();

    int b8 = rowbase >> 10;
    int rloc = rowbase & 1023;
    if (blockIdx.y == 1) {
        // K: strip-swizzled; 2048 16B units: u -> (dc, s, cl)
#pragma unroll
        for (int o = 0; o < 4; o++) {
            int u = o * 512 + t;
            int dc = u >> 8, s = (u >> 6) & 3, cl = u & 63;
            int gg = s ^ (cl & 3);
            int4 v = *reinterpret_cast<const int4*>(&sbuf[cl * 296 + dc * 32 + gg * 8]);
            size_t idx = (((size_t)b8 * 8 + dc) * 4 + s) * 8192 + (size_t)(rloc + cl) * 8;
            *reinterpret_cast<int4*>(outp + idx) = v;
        }
    } else {
        // Q: fragment layout
#pragma unroll
        for (int o = 0; o < 4; o++) {
            int gu = o * 512 + t;
            int dc = gu >> 8;
            int rem = gu & 255;
            int row = rem >> 2, kseg = rem & 3;
            int4 v = *reinterpret_cast<const int4*>(&sbuf[row * 296 + dc * 32 + kseg * 8]);
            size_t idx = (((size_t)b8 * 8 + dc) * 1024 + rloc + row) * 32 + kseg * 8;
            *reinterpret_cast<int4*>(outp + idx) = v;
        }
    }
}

// ---------------- kernel 3: fused QK^T + tanh-clip + mask + log_softmax ----------------
// 1024 threads, 64 q-rows/block. K chunk (64KB) staged once per dc via
// global_load_lds, shared by all 16 waves -> 8x less L2 traffic than per-wave
// direct loads. Epilogue: 2 parks of 32 rows, lgkm-only barriers, NT stores.
__global__ __launch_bounds__(1024, 4)
void attn_kernel(const short* __restrict__ Qs, const short* __restrict__ Ks,
                 const unsigned* __restrict__ pmask, float* __restrict__ out) {
    const int RS = 1028;
    __shared__ __align__(16) char slds[32 * RS * 4];   // 131584B: K chunk (64KB) / park overlay

    char* kldsb = slds;
    float* plds = (float*)slds;

    int t = threadIdx.x;
    int lane = t & 63, wv = t >> 6;
    int l15 = lane & 15, g = lane >> 4;
    int rowg = wv >> 3, colg = wv & 7;

    // XCD swizzle: 1024 blocks -> 128/XCD = 8 whole batches per XCD
    int bid = blockIdx.x;
    int wg = (bid & 7) * 128 + (bid >> 3);
    int b = wg >> 4;
    int brow = (wg & 15) * 64;

    // packed mask prefetch: park p word = pm[p*1024 + t]
    const unsigned* pm = pmask + ((size_t)b * 1024 + brow) * 32;
    unsigned mw0 = pm[t];
    unsigned mw1 = pm[1024 + t];

    const short* qb = Qs + (size_t)b * 8 * 32768;
    const char* kbb = (const char*)(Ks + (size_t)b * 8 * 32768);

    f32x4 zero = {0.f, 0.f, 0.f, 0.f};
    f32x4 acc[2][8];
#pragma unroll
    for (int m = 0; m < 2; m++)
#pragma unroll
        for (int n = 0; n < 8; n++) acc[m][n] = zero;

    // per-lane K fragment base byte offset (strip s = g ^ (l15&3))
    int kfoff = ((g ^ (l15 & 3)) << 14) + (colg * 128 + l15) * 16;

    for (int dc = 0; dc < 8; dc++) {
        LGKM_BAR();                       // prior ds reads done before overwrite
        const char* kcb = kbb + dc * 65536;
        int soff = wv << 12;              // wave's 4KB strip of the chunk
#pragma unroll
        for (int i = 0; i < 4; i++) {
            int boff = soff + (i << 10);
            GLOAD_LDS16(kcb + boff + lane * 16, kldsb + boff);
        }
        const short* qc = qb + dc * 32768;
        bf16x8 a0 = *reinterpret_cast<const bf16x8*>(qc + (brow + rowg * 32 + l15) * 32 + g * 8);
        bf16x8 a1 = *reinterpret_cast<const bf16x8*>(qc + (brow + rowg * 32 + 16 + l15) * 32 + g * 8);
        VM_BAR();                         // staged K (and Q) resident
#pragma unroll
        for (int n = 0; n < 8; n++) {
            bf16x8 bf = *reinterpret_cast<const bf16x8*>(kldsb + kfoff + n * 256);
            acc[0][n] = __builtin_amdgcn_mfma_f32_16x16x32_bf16(a0, bf, acc[0][n], 0, 0, 0);
            acc[1][n] = __builtin_amdgcn_mfma_f32_16x16x32_bf16(a1, bf, acc[1][n], 0, 0, 0);
        }
    }

    int prow = t >> 5;        // 0..31 park row
    int j = t & 31;
    float* urow = plds + prow * RS;

#pragma unroll
    for (int p = 0; p < 2; p++) {
        LGKM_BAR();           // all prior ds reads done (K frags / prev park)
        if (rowg == p) {      // wave-uniform branch
#pragma unroll
            for (int m = 0; m < 2; m++)
#pragma unroll
                for (int n = 0; n < 8; n++)
#pragma unroll
                    for (int r = 0; r < 4; r++)
                        plds[(m * 16 + g * 4 + r) * RS + colg * 128 + n * 16 + l15] = acc[m][n][r];
        }
        LGKM_BAR();

        unsigned bits = p ? mw1 : mw0;
        float psum = 0.f;
#pragma unroll
        for (int i = 0; i < 8; i++) {
            int col = j * 4 + i * 128;
            float4 u4 = *reinterpret_cast<const float4*>(urow + col);
            float uv[4] = {u4.x, u4.y, u4.z, u4.w};
            float uc[4];
#pragma unroll
            for (int c = 0; c < 4; c++) {
                float e2 = __expf(2.0f * uv[c]);
                float tc = 10.0f - 20.0f / (e2 + 1.0f);   // 10*tanh(u)
                bool msk = (bits >> (i * 4 + c)) & 1;
                uc[c] = msk ? NEG_INF : tc;
                psum += msk ? 0.0f : __expf(tc);
            }
            float4 s = {uc[0], uc[1], uc[2], uc[3]};
            *reinterpret_cast<float4*>(urow + col) = s;
        }
        psum += __shfl_xor(psum, 1);
        psum += __shfl_xor(psum, 2);
        psum += __shfl_xor(psum, 4);
        psum += __shfl_xor(psum, 8);
        psum += __shfl_xor(psum, 16);
        float lse = __logf(fmaxf(psum, 1e-30f));
        float lse0 = __shfl(lse, 0);    // park row 2wv
        float lse1 = __shfl(lse, 32);   // park row 2wv+1

        // pass 2: wave wv owns park rows 2wv, 2wv+1 (it wrote them in pass 1)
        float* obase = out + ((size_t)b * 1024 + brow + p * 32) * 1024;
#pragma unroll
        for (int rr = 0; rr < 2; rr++) {
            int r2 = wv * 2 + rr;
            float lser = rr ? lse1 : lse0;
            const float* ur2 = plds + r2 * RS;
            float* orow = obase + (size_t)r2 * 1024;
#pragma unroll
            for (int i2 = 0; i2 < 4; i2++) {
                int col = lane * 4 + i2 * 256;
                float4 u4 = *reinterpret_cast<const float4*>(ur2 + col);
                f32x4 o = {u4.x - lser, u4.y - lser, u4.z - lser, u4.w - lser};
                __builtin_nontemporal_store(o, reinterpret_cast<f32x4*>(orow + col));
            }
        }
    }
}

extern "C" void kernel_launch(void* const* d_in, const int* in_sizes, int n_in,
                              void* d_out, int out_size, void* d_ws, size_t ws_size,
                              hipStream_t stream) {
    const float* q  = (const float*)d_in[0];
    const float* k  = (const float*)d_in[1];
    const float* wq = (const float*)d_in[2];
    const float* wk = (const float*)d_in[3];
    const int* mask = (const int*)d_in[4];
    float* out = (float*)d_out;

    char* ws = (char*)d_ws;
    short* wtq = (short*)ws;                                  // 128KB
    short* wtk = (short*)(ws + 131072);                       // 128KB
    short* Qb  = (short*)(ws + 262144);                       // 32MB
    short* Kb  = (short*)(ws + 262144 + 33554432);            // 32MB
    unsigned* pmask = (unsigned*)(ws + 262144 + 2 * 33554432); // 8.4MB

    wtrans_kernel<<<dim3(8, 8, 2), dim3(32, 8), 0, stream>>>(wq, wk, wtq, wtk);
    proj_kernel<<<dim3(1024, 3), 512, 0, stream>>>(q, k, wtq, wtk, Qb, Kb, mask, pmask);
    attn_kernel<<<dim3(1024), 1024, 0, stream>>>(Qb, Kb, pmask, out);
}